// Round 7
// baseline (1398.972 us; speedup 1.0000x reference)
//
#include <hip/hip_runtime.h>
#include <hip/hip_fp16.h>

#define NN 100000     // num nodes
#define NE 1600000    // num edges
#define NEL 200000    // link-pred edges

// Bucketed partition (R22): bucket = dst >> 8 (256 dst nodes per bucket).
// k_build is ELIMINATED — gathers consume part[] directly with LDS f32
// accumulators (order change only affects f32 accumulation, ~1e-6; the
// 2^-10 absmax is fp16 message quantization, order-independent).
#define NBUCK 391     // ceil(NN/256)
#define CAPB  4608    // per-bucket capacity (mean 4096, sigma ~64 -> 8 sigma;
                      // R5 measured-pass at 4800 => actual max ~4300)
#define TPE   2048    // edges per k_part block
#define EPT   8       // edges per thread in k_part
#define NPART 782     // ceil(NE/TPE)

typedef short s16x8 __attribute__((ext_vector_type(8)));
typedef float f32x4 __attribute__((ext_vector_type(4)));

__device__ __forceinline__ unsigned short bf16hi(float v) {
    unsigned u = __float_as_uint(v);
    return (unsigned short)((u + 0x7FFFu + ((u >> 16) & 1u)) >> 16);
}
__device__ __forceinline__ float bf16tof(unsigned short b) {
    return __uint_as_float(((unsigned)b) << 16);
}

// ---------------- pass A: partition edges into buckets + per-node degree ---
// Register-staged (R5 version, measured-correct) + global atomicAdd deg[d].
__global__ __launch_bounds__(256) void k_part(const int* __restrict__ src,
                                              const int* __restrict__ dst,
                                              int* __restrict__ gcur,
                                              int* __restrict__ deg,
                                              int* __restrict__ part) {
    __shared__ int hist[NBUCK];
    __shared__ int base[NBUCK];
    __shared__ int rk[NBUCK];
    int tid = threadIdx.x;
    for (int i = tid; i < NBUCK; i += 256) { hist[i] = 0; rk[i] = 0; }
    __syncthreads();
    int e0 = blockIdx.x * TPE;
    int d[EPT], s[EPT];
#pragma unroll
    for (int k = 0; k < EPT; ++k) {
        int e = e0 + tid + k * 256;
        bool ok = e < NE;
        d[k] = ok ? dst[e] : -1;
        s[k] = ok ? src[e] : 0;
    }
#pragma unroll
    for (int k = 0; k < EPT; ++k)
        if (d[k] >= 0) {
            atomicAdd(&hist[d[k] >> 8], 1);
            atomicAdd(&deg[d[k]], 1);          // per-node in-degree
        }
    __syncthreads();
    for (int i = tid; i < NBUCK; i += 256)
        if (hist[i]) base[i] = i * CAPB + atomicAdd(&gcur[i], hist[i]);
    __syncthreads();
#pragma unroll
    for (int k = 0; k < EPT; ++k)
        if (d[k] >= 0) {
            int b = d[k] >> 8;
            int r = atomicAdd(&rk[b], 1);
            part[base[b] + r] = ((d[k] & 255) << 17) | s[k];   // src < 2^17
        }
}

// ---------------- hw1' = dinv * ([x|pos] @ W1)  (80 -> 64), MFMA bf16-split
// bf16 hi/lo split (Ahi*Bhi + Ahi*Blo + Alo*Bhi) -> fp32-class accuracy.
// dinv computed on the fly from deg (rsqrt(deg+1)).
#define HW1_K 104
__global__ __launch_bounds__(256) void k_hw1(const float* __restrict__ x,
                                             const float* __restrict__ pos,
                                             const float* __restrict__ W1,
                                             const int* __restrict__ deg,
                                             __half* __restrict__ hw1) {
    __shared__ unsigned short ahi[64 * HW1_K];
    __shared__ unsigned short alo[64 * HW1_K];
    __shared__ unsigned short bhi[64 * HW1_K];
    __shared__ unsigned short blo[64 * HW1_K];
    __shared__ float sdin[64];
    int tid = threadIdx.x;
    int nb = blockIdx.x * 64;
    for (int i = tid; i < 64 * 24; i += 256) {
        int r = i / 24, c = i - r * 24;
        ahi[r * HW1_K + 80 + c] = 0; alo[r * HW1_K + 80 + c] = 0;
        bhi[r * HW1_K + 80 + c] = 0; blo[r * HW1_K + 80 + c] = 0;
    }
    for (int i = tid; i < 64 * 64; i += 256) {
        int r = i >> 6, c = i & 63;
        int g = nb + r;
        float v = (g < NN) ? x[g * 64 + c] : 0.0f;
        unsigned short h = bf16hi(v);
        ahi[r * HW1_K + c] = h;
        alo[r * HW1_K + c] = bf16hi(v - bf16tof(h));
    }
    for (int i = tid; i < 64 * 16; i += 256) {
        int r = i >> 4, c = i & 15;
        int g = nb + r;
        float v = (g < NN) ? pos[g * 16 + c] : 0.0f;
        unsigned short h = bf16hi(v);
        ahi[r * HW1_K + 64 + c] = h;
        alo[r * HW1_K + 64 + c] = bf16hi(v - bf16tof(h));
    }
    for (int i = tid; i < 80 * 64; i += 256) {
        int k = i >> 6, c = i & 63;
        float v = W1[i];
        unsigned short h = bf16hi(v);
        bhi[c * HW1_K + k] = h;
        blo[c * HW1_K + k] = bf16hi(v - bf16tof(h));
    }
    for (int i = tid; i < 64; i += 256) {
        int g = nb + i;
        sdin[i] = (g < NN) ? rsqrtf((float)(deg[g] + 1)) : 0.0f;
    }
    __syncthreads();
    int wave = tid >> 6, lane = tid & 63;
    int frow = lane & 15, fq = lane >> 4;
    int r0 = wave * 16;                        // wave owns 16 rows x 64 cols
    int aoff = (r0 + frow) * HW1_K + fq * 8;
    s16x8 ah0 = *(s16x8*)&ahi[aoff];
    s16x8 ah1 = *(s16x8*)&ahi[aoff + 32];
    s16x8 ah2 = *(s16x8*)&ahi[aoff + 64];
    s16x8 al0 = *(s16x8*)&alo[aoff];
    s16x8 al1 = *(s16x8*)&alo[aoff + 32];
    s16x8 al2 = *(s16x8*)&alo[aoff + 64];
    f32x4 acc[4];
#pragma unroll
    for (int ct = 0; ct < 4; ++ct) {
        acc[ct] = (f32x4)(0.0f);
        int boff = (ct * 16 + frow) * HW1_K + fq * 8;
        s16x8 bh0 = *(s16x8*)&bhi[boff];
        s16x8 bh1 = *(s16x8*)&bhi[boff + 32];
        s16x8 bh2 = *(s16x8*)&bhi[boff + 64];
        s16x8 bl0 = *(s16x8*)&blo[boff];
        s16x8 bl1 = *(s16x8*)&blo[boff + 32];
        s16x8 bl2 = *(s16x8*)&blo[boff + 64];
        acc[ct] = __builtin_amdgcn_mfma_f32_16x16x32_bf16(ah0, bh0, acc[ct], 0, 0, 0);
        acc[ct] = __builtin_amdgcn_mfma_f32_16x16x32_bf16(ah1, bh1, acc[ct], 0, 0, 0);
        acc[ct] = __builtin_amdgcn_mfma_f32_16x16x32_bf16(ah2, bh2, acc[ct], 0, 0, 0);
        acc[ct] = __builtin_amdgcn_mfma_f32_16x16x32_bf16(ah0, bl0, acc[ct], 0, 0, 0);
        acc[ct] = __builtin_amdgcn_mfma_f32_16x16x32_bf16(ah1, bl1, acc[ct], 0, 0, 0);
        acc[ct] = __builtin_amdgcn_mfma_f32_16x16x32_bf16(ah2, bl2, acc[ct], 0, 0, 0);
        acc[ct] = __builtin_amdgcn_mfma_f32_16x16x32_bf16(al0, bh0, acc[ct], 0, 0, 0);
        acc[ct] = __builtin_amdgcn_mfma_f32_16x16x32_bf16(al1, bh1, acc[ct], 0, 0, 0);
        acc[ct] = __builtin_amdgcn_mfma_f32_16x16x32_bf16(al2, bh2, acc[ct], 0, 0, 0);
    }
#pragma unroll
    for (int ct = 0; ct < 4; ++ct) {
        int col = ct * 16 + frow;
#pragma unroll
        for (int i = 0; i < 4; ++i) {
            int r = r0 + fq * 4 + i;           // C/D: col=lane&15, row=(lane>>4)*4+i
            int g = nb + r;
            if (g < NN)
                hw1[g * 64 + col] = __float2half_rn(acc[ct][i] * sdin[r]);
        }
    }
}

// ---------------- layer-1 gather, bucket-direct (one block per bucket) -----
// LDS f32 accumulator [256 dst][64 ch] = 64 KB; 8 waves each own a chunk of
// the bucket's edge list. Same proven edge loop shape as R18: scalar part[]
// recs (16-deep), full 64-lane row fetch per edge, s0-clamp for the partial
// batch + arithmetic correction (-inv*g0 into acc[dl0]).
// Landmines: R15 channel-slicing 3.2x; R16 index arrays 5x (spill);
// R6 megakernel 4.4x (occupancy + K$ demotion) — keep separate dispatches.
__global__ __launch_bounds__(512) void k_gather1(const int* __restrict__ gcur,
                                                 const int* __restrict__ part,
                                                 const int* __restrict__ deg,
                                                 const __half* __restrict__ hw,
                                                 const float* __restrict__ b1,
                                                 __half* __restrict__ h2out) {
    __shared__ float acc[256 * 64];            // 64 KB -> 2 blocks/CU, all 391 resident
    int tid = threadIdx.x;
    int b = blockIdx.x;
    int lane = tid & 63;
    int w = tid >> 6;                          // 8 waves
    for (int i = tid; i < 256 * 64; i += 512) acc[i] = 0.0f;
    __syncthreads();
    int cnt = gcur[b];
    int pbase = b * CAPB;
    int chunk = (cnt + 7) >> 3;
    int ws = __builtin_amdgcn_readfirstlane(w * chunk);   // wave-uniform SGPR
    int we = min(ws + chunk, cnt);
    for (int e = ws; e < we; e += 16) {
        int rem = we - e;                      // >= 1 (SGPR)
        int p0 = pbase + e;
        int r0  = part[p0];
        int r1  = (rem > 1)  ? part[p0 + 1]  : r0;
        int r2  = (rem > 2)  ? part[p0 + 2]  : r0;
        int r3  = (rem > 3)  ? part[p0 + 3]  : r0;
        int r4  = (rem > 4)  ? part[p0 + 4]  : r0;
        int r5  = (rem > 5)  ? part[p0 + 5]  : r0;
        int r6  = (rem > 6)  ? part[p0 + 6]  : r0;
        int r7  = (rem > 7)  ? part[p0 + 7]  : r0;
        int r8  = (rem > 8)  ? part[p0 + 8]  : r0;
        int r9  = (rem > 9)  ? part[p0 + 9]  : r0;
        int r10 = (rem > 10) ? part[p0 + 10] : r0;
        int r11 = (rem > 11) ? part[p0 + 11] : r0;
        int r12 = (rem > 12) ? part[p0 + 12] : r0;
        int r13 = (rem > 13) ? part[p0 + 13] : r0;
        int r14 = (rem > 14) ? part[p0 + 14] : r0;
        int r15 = (rem > 15) ? part[p0 + 15] : r0;
        float g0  = __half2float(hw[(r0  & 0x1FFFF) * 64 + lane]);
        float g1  = __half2float(hw[(r1  & 0x1FFFF) * 64 + lane]);
        float g2  = __half2float(hw[(r2  & 0x1FFFF) * 64 + lane]);
        float g3  = __half2float(hw[(r3  & 0x1FFFF) * 64 + lane]);
        float g4  = __half2float(hw[(r4  & 0x1FFFF) * 64 + lane]);
        float g5  = __half2float(hw[(r5  & 0x1FFFF) * 64 + lane]);
        float g6  = __half2float(hw[(r6  & 0x1FFFF) * 64 + lane]);
        float g7  = __half2float(hw[(r7  & 0x1FFFF) * 64 + lane]);
        float g8  = __half2float(hw[(r8  & 0x1FFFF) * 64 + lane]);
        float g9  = __half2float(hw[(r9  & 0x1FFFF) * 64 + lane]);
        float g10 = __half2float(hw[(r10 & 0x1FFFF) * 64 + lane]);
        float g11 = __half2float(hw[(r11 & 0x1FFFF) * 64 + lane]);
        float g12 = __half2float(hw[(r12 & 0x1FFFF) * 64 + lane]);
        float g13 = __half2float(hw[(r13 & 0x1FFFF) * 64 + lane]);
        float g14 = __half2float(hw[(r14 & 0x1FFFF) * 64 + lane]);
        float g15 = __half2float(hw[(r15 & 0x1FFFF) * 64 + lane]);
        int inv = 16 - rem;
        if (inv < 0) inv = 0;                  // # clamped slots (SGPR)
        atomicAdd(&acc[(r0  >> 17) * 64 + lane], g0);
        atomicAdd(&acc[(r1  >> 17) * 64 + lane], g1);
        atomicAdd(&acc[(r2  >> 17) * 64 + lane], g2);
        atomicAdd(&acc[(r3  >> 17) * 64 + lane], g3);
        atomicAdd(&acc[(r4  >> 17) * 64 + lane], g4);
        atomicAdd(&acc[(r5  >> 17) * 64 + lane], g5);
        atomicAdd(&acc[(r6  >> 17) * 64 + lane], g6);
        atomicAdd(&acc[(r7  >> 17) * 64 + lane], g7);
        atomicAdd(&acc[(r8  >> 17) * 64 + lane], g8);
        atomicAdd(&acc[(r9  >> 17) * 64 + lane], g9);
        atomicAdd(&acc[(r10 >> 17) * 64 + lane], g10);
        atomicAdd(&acc[(r11 >> 17) * 64 + lane], g11);
        atomicAdd(&acc[(r12 >> 17) * 64 + lane], g12);
        atomicAdd(&acc[(r13 >> 17) * 64 + lane], g13);
        atomicAdd(&acc[(r14 >> 17) * 64 + lane], g14);
        atomicAdd(&acc[(r15 >> 17) * 64 + lane], g15);
        atomicAdd(&acc[(r0  >> 17) * 64 + lane], -(float)inv * g0);  // undo clamps
    }
    __syncthreads();
    for (int r = w; r < 256; r += 8) {         // epilogue: wave per row
        int g = b * 256 + r;
        if (g < NN) {
            float dd = rsqrtf((float)(deg[g] + 1));
            float hself = __half2float(hw[g * 64 + lane]);
            float v = fmaxf(b1[lane] + dd * (acc[r * 64 + lane] + hself), 0.0f);
            h2out[g * 64 + lane] = __float2half_rn(v);
        }
    }
}

// ---------------- hw2' = dinv * (h2 @ W2)  (64 -> 32), MFMA bf16-split -----
#define HW2_K 72
__global__ __launch_bounds__(256) void k_hw2(const __half* __restrict__ h2,
                                             const float* __restrict__ W2,
                                             const int* __restrict__ deg,
                                             __half* __restrict__ hw2) {
    __shared__ unsigned short ahi[128 * HW2_K];
    __shared__ unsigned short alo[128 * HW2_K];
    __shared__ unsigned short bhi[32 * HW2_K];
    __shared__ unsigned short blo[32 * HW2_K];
    __shared__ float sdin[128];
    int tid = threadIdx.x;
    int nb = blockIdx.x * 128;
    for (int i = tid; i < 128 * 32; i += 256) {
        int r = i >> 5, cp = i & 31;
        int g = nb + r;
        __half2 hv = (g < NN) ? ((const __half2*)h2)[g * 32 + cp]
                              : __floats2half2_rn(0.0f, 0.0f);
        float2 f = __half22float2(hv);
        unsigned short h0 = bf16hi(f.x), h1 = bf16hi(f.y);
        ahi[r * HW2_K + 2 * cp]     = h0;
        ahi[r * HW2_K + 2 * cp + 1] = h1;
        alo[r * HW2_K + 2 * cp]     = bf16hi(f.x - bf16tof(h0));
        alo[r * HW2_K + 2 * cp + 1] = bf16hi(f.y - bf16tof(h1));
    }
    for (int i = tid; i < 64 * 32; i += 256) {
        int k = i >> 5, c = i & 31;
        float v = W2[i];
        unsigned short h = bf16hi(v);
        bhi[c * HW2_K + k] = h;
        blo[c * HW2_K + k] = bf16hi(v - bf16tof(h));
    }
    for (int i = tid; i < 128; i += 256) {
        int g = nb + i;
        sdin[i] = (g < NN) ? rsqrtf((float)(deg[g] + 1)) : 0.0f;
    }
    __syncthreads();
    int wave = tid >> 6, lane = tid & 63;
    int frow = lane & 15, fq = lane >> 4;
    int r0 = wave * 32;                        // wave owns 32 rows x 32 cols
    f32x4 acc[2][2];
#pragma unroll
    for (int rt = 0; rt < 2; ++rt) {
        int aoff = (r0 + rt * 16 + frow) * HW2_K + fq * 8;
        s16x8 ah0 = *(s16x8*)&ahi[aoff];
        s16x8 ah1 = *(s16x8*)&ahi[aoff + 32];
        s16x8 al0 = *(s16x8*)&alo[aoff];
        s16x8 al1 = *(s16x8*)&alo[aoff + 32];
#pragma unroll
        for (int ct = 0; ct < 2; ++ct) {
            acc[rt][ct] = (f32x4)(0.0f);
            int boff = (ct * 16 + frow) * HW2_K + fq * 8;
            s16x8 bh0 = *(s16x8*)&bhi[boff];
            s16x8 bh1 = *(s16x8*)&bhi[boff + 32];
            s16x8 bl0 = *(s16x8*)&blo[boff];
            s16x8 bl1 = *(s16x8*)&blo[boff + 32];
            acc[rt][ct] = __builtin_amdgcn_mfma_f32_16x16x32_bf16(ah0, bh0, acc[rt][ct], 0, 0, 0);
            acc[rt][ct] = __builtin_amdgcn_mfma_f32_16x16x32_bf16(ah1, bh1, acc[rt][ct], 0, 0, 0);
            acc[rt][ct] = __builtin_amdgcn_mfma_f32_16x16x32_bf16(ah0, bl0, acc[rt][ct], 0, 0, 0);
            acc[rt][ct] = __builtin_amdgcn_mfma_f32_16x16x32_bf16(ah1, bl1, acc[rt][ct], 0, 0, 0);
            acc[rt][ct] = __builtin_amdgcn_mfma_f32_16x16x32_bf16(al0, bh0, acc[rt][ct], 0, 0, 0);
            acc[rt][ct] = __builtin_amdgcn_mfma_f32_16x16x32_bf16(al1, bh1, acc[rt][ct], 0, 0, 0);
        }
    }
#pragma unroll
    for (int rt = 0; rt < 2; ++rt)
#pragma unroll
        for (int ct = 0; ct < 2; ++ct) {
            int col = ct * 16 + frow;
#pragma unroll
            for (int i = 0; i < 4; ++i) {
                int r = r0 + rt * 16 + fq * 4 + i;
                int g = nb + r;
                if (g < NN)
                    hw2[g * 32 + col] = __float2half_rn(acc[rt][ct][i] * sdin[r]);
            }
        }
}

// ---------------- layer-2 gather, bucket-direct + z + linkpred dots --------
// LDS acc [256 dst][32 ch] = 32 KB; half-wave (32 lanes) per 64B row, so each
// load instruction covers 2 edges (same as R18 g2). Monotone clamp: slot 7
// (gH) holds the clamped r0 value whenever inv > 0.
__global__ __launch_bounds__(512) void k_gather2(const int* __restrict__ gcur,
                                                 const int* __restrict__ part,
                                                 const int* __restrict__ deg,
                                                 const __half* __restrict__ hw,
                                                 const float* __restrict__ b2,
                                                 const float* __restrict__ Wl,
                                                 float* __restrict__ outz,
                                                 float* __restrict__ uu,
                                                 float* __restrict__ vv) {
    __shared__ float acc[256 * 32];            // 32 KB
    int tid = threadIdx.x;
    int b = blockIdx.x;
    int lane = tid & 63;
    int w = tid >> 6;
    int half = lane >> 5;
    int j = lane & 31;
    for (int i = tid; i < 256 * 32; i += 512) acc[i] = 0.0f;
    __syncthreads();
    int cnt = gcur[b];
    int pbase = b * CAPB;
    int chunk = (cnt + 7) >> 3;
    int ws = __builtin_amdgcn_readfirstlane(w * chunk);
    int we = min(ws + chunk, cnt);
    for (int e = ws; e < we; e += 16) {
        int rem = we - e;
        int p0 = pbase + e;
        int r0  = part[p0];
        int r1  = (rem > 1)  ? part[p0 + 1]  : r0;
        int r2  = (rem > 2)  ? part[p0 + 2]  : r0;
        int r3  = (rem > 3)  ? part[p0 + 3]  : r0;
        int r4  = (rem > 4)  ? part[p0 + 4]  : r0;
        int r5  = (rem > 5)  ? part[p0 + 5]  : r0;
        int r6  = (rem > 6)  ? part[p0 + 6]  : r0;
        int r7  = (rem > 7)  ? part[p0 + 7]  : r0;
        int r8  = (rem > 8)  ? part[p0 + 8]  : r0;
        int r9  = (rem > 9)  ? part[p0 + 9]  : r0;
        int r10 = (rem > 10) ? part[p0 + 10] : r0;
        int r11 = (rem > 11) ? part[p0 + 11] : r0;
        int r12 = (rem > 12) ? part[p0 + 12] : r0;
        int r13 = (rem > 13) ? part[p0 + 13] : r0;
        int r14 = (rem > 14) ? part[p0 + 14] : r0;
        int r15 = (rem > 15) ? part[p0 + 15] : r0;
        int cA = half ? r1  : r0;              // slot k covers edges e+2k+half
        int cB = half ? r3  : r2;
        int cC = half ? r5  : r4;
        int cD = half ? r7  : r6;
        int cE = half ? r9  : r8;
        int cF = half ? r11 : r10;
        int cG = half ? r13 : r12;
        int cH = half ? r15 : r14;
        float gA = __half2float(hw[(cA & 0x1FFFF) * 32 + j]);
        float gB = __half2float(hw[(cB & 0x1FFFF) * 32 + j]);
        float gC = __half2float(hw[(cC & 0x1FFFF) * 32 + j]);
        float gD = __half2float(hw[(cD & 0x1FFFF) * 32 + j]);
        float gE = __half2float(hw[(cE & 0x1FFFF) * 32 + j]);
        float gF = __half2float(hw[(cF & 0x1FFFF) * 32 + j]);
        float gG = __half2float(hw[(cG & 0x1FFFF) * 32 + j]);
        float gH = __half2float(hw[(cH & 0x1FFFF) * 32 + j]);
        int nv = (rem - half + 1) >> 1;        // valid slots this half
        if (nv > 8) nv = 8;
        if (nv < 0) nv = 0;
        int inv = 8 - nv;
        atomicAdd(&acc[(cA >> 17) * 32 + j], gA);
        atomicAdd(&acc[(cB >> 17) * 32 + j], gB);
        atomicAdd(&acc[(cC >> 17) * 32 + j], gC);
        atomicAdd(&acc[(cD >> 17) * 32 + j], gD);
        atomicAdd(&acc[(cE >> 17) * 32 + j], gE);
        atomicAdd(&acc[(cF >> 17) * 32 + j], gF);
        atomicAdd(&acc[(cG >> 17) * 32 + j], gG);
        atomicAdd(&acc[(cH >> 17) * 32 + j], gH);
        atomicAdd(&acc[(r0 >> 17) * 32 + j], -(float)inv * gH);  // gH==hw[s0] when inv>0
    }
    __syncthreads();
    int hwid = w * 2 + half;                   // 16 half-waves, row each
    for (int r = hwid; r < 256; r += 16) {
        int g = b * 256 + r;
        if (g < NN) {                          // uniform per half-wave
            float dd = rsqrtf((float)(deg[g] + 1));
            float hself = __half2float(hw[g * 32 + j]);
            float z = b2[j] + dd * (acc[r * 32 + j] + hself);
            outz[g * 32 + j] = z;
            float p0 = z * Wl[j];
            float p1 = z * Wl[32 + j];
            p0 += __shfl_xor(p0, 1, 64);  p1 += __shfl_xor(p1, 1, 64);
            p0 += __shfl_xor(p0, 2, 64);  p1 += __shfl_xor(p1, 2, 64);
            p0 += __shfl_xor(p0, 4, 64);  p1 += __shfl_xor(p1, 4, 64);
            p0 += __shfl_xor(p0, 8, 64);  p1 += __shfl_xor(p1, 8, 64);
            p0 += __shfl_xor(p0, 16, 64); p1 += __shfl_xor(p1, 16, 64);
            if (j == 0) { uu[g] = p0; vv[g] = p1; }
        }
    }
}

// ---------------- link prediction head: pred = u[s] + v[d] + bl ------------
// (also retires deg's scratch space by overwriting out_pred)
__global__ __launch_bounds__(256) void k_linkpred(const int* __restrict__ sidx,
                                                  const int* __restrict__ didx,
                                                  const float* __restrict__ uu,
                                                  const float* __restrict__ vv,
                                                  const float* __restrict__ bl,
                                                  float* __restrict__ pred) {
    int e = blockIdx.x * 256 + threadIdx.x;
    if (e < NEL)
        pred[e] = uu[sidx[e]] + vv[didx[e]] + bl[0];
}

extern "C" void kernel_launch(void* const* d_in, const int* in_sizes, int n_in,
                              void* d_out, int out_size, void* d_ws, size_t ws_size,
                              hipStream_t stream) {
    const float* x    = (const float*)d_in[0];
    const float* pos  = (const float*)d_in[1];
    const float* W1   = (const float*)d_in[2];
    const float* b1   = (const float*)d_in[3];
    const float* W2   = (const float*)d_in[4];
    const float* b2   = (const float*)d_in[5];
    const float* Wl   = (const float*)d_in[6];
    const float* bl   = (const float*)d_in[7];
    const int*   ei   = (const int*)d_in[8];   // [2, NE]
    const int*   eli  = (const int*)d_in[9];   // [2, NEL]
    const int* src  = ei;
    const int* dst  = ei + NE;
    const int* lsrc = eli;
    const int* ldst = eli + NEL;

    float* out_z    = (float*)d_out;            // [NN, 32]
    float* out_pred = (float*)d_out + NN * 32;  // [NEL]

    // workspace: gcur[512 pad]i | part[NBUCK*CAPB]i (7.2 MB, live through
    // k_gather2; provides slack for <=15-int over-reads) | hw1'[NN*64]h |
    // h2[NN*64]h (dead after k_hw2 -> uu/vv) | hw2'[NN*32]h  ~= 39.2 MB.
    // deg[NN]i lives in out_pred's region (scratch until k_linkpred
    // overwrites it — pred is written only in the final kernel).
    int*    gcur  = (int*)d_ws;
    int*    part  = gcur + 512;
    __half* hw1   = (__half*)(part + NBUCK * CAPB);
    __half* h2    = hw1 + NN * 64;
    __half* hw2   = h2 + NN * 64;
    float*  uu    = (float*)h2;                 // h2 dead after k_hw2
    float*  vv    = uu + NN;
    int*    deg   = (int*)out_pred;             // NEL*4 >= NN*4

    // 1) zero bucket counters + per-node degree
    hipMemsetAsync(gcur, 0, NBUCK * sizeof(int), stream);
    hipMemsetAsync(deg, 0, NN * sizeof(int), stream);

    // 2) partition edges into buckets + degree count
    k_part<<<NPART, 256, 0, stream>>>(src, dst, gcur, deg, part);

    // 3) hw1' = dinv * ([x|pos] @ W1), MFMA bf16-split
    k_hw1<<<(NN + 63) / 64, 256, 0, stream>>>(x, pos, W1, deg, hw1);

    // 4) layer-1 gather (bucket-direct, LDS accumulate) -> h2
    k_gather1<<<NBUCK, 512, 0, stream>>>(gcur, part, deg, hw1, b1, h2);

    // 5) hw2' = dinv * (h2 @ W2), MFMA bf16-split
    k_hw2<<<(NN + 127) / 128, 256, 0, stream>>>(h2, W2, deg, hw2);

    // 6) layer-2 gather (bucket-direct) -> z + linkpred dots u,v
    k_gather2<<<NBUCK, 512, 0, stream>>>(gcur, part, deg, hw2, b2, Wl,
                                         out_z, uu, vv);

    // 7) link prediction: pred = u[s] + v[d] + bl (overwrites deg scratch)
    k_linkpred<<<(NEL + 255) / 256, 256, 0, stream>>>(lsrc, ldst, uu, vv, bl,
                                                      out_pred);
}

// Round 8
// 280.243 us; speedup vs baseline: 4.9920x; 4.9920x over previous
//
#include <hip/hip_runtime.h>
#include <hip/hip_fp16.h>

#define NN 100000     // num nodes
#define NE 1600000    // num edges
#define NEL 200000    // link-pred edges
#define TM 64         // nodes per block in k_hw1

// Bucketed CSR build (R12 config — best measured): bucket = dst >> 9.
#define NBUCK 196     // ceil(NN/512)
#define CAPB  10240   // per-bucket capacity (mean 8163, sigma ~90)
#define TPE   8192    // edges per k_part block (196 blocks)

typedef short s16x8 __attribute__((ext_vector_type(8)));
typedef float f32x4 __attribute__((ext_vector_type(4)));

__device__ __forceinline__ unsigned short bf16hi(float v) {
    unsigned u = __float_as_uint(v);
    return (unsigned short)((u + 0x7FFFu + ((u >> 16) & 1u)) >> 16);
}
__device__ __forceinline__ float bf16tof(unsigned short b) {
    return __uint_as_float(((unsigned)b) << 16);
}

// ---------------- CSR build, pass A: partition edges into buckets ----------
__global__ __launch_bounds__(256) void k_part(const int* __restrict__ src,
                                              const int* __restrict__ dst,
                                              int* __restrict__ gcur,
                                              int* __restrict__ part) {
    __shared__ int hist[NBUCK];
    __shared__ int base[NBUCK];
    __shared__ int rk[NBUCK];
    int tid = threadIdx.x;
    for (int i = tid; i < NBUCK; i += 256) { hist[i] = 0; rk[i] = 0; }
    __syncthreads();
    int e0 = blockIdx.x * TPE;
    int e1 = min(e0 + TPE, NE);
    for (int e = e0 + tid; e < e1; e += 256)
        atomicAdd(&hist[dst[e] >> 9], 1);
    __syncthreads();
    for (int i = tid; i < NBUCK; i += 256)
        base[i] = i * CAPB + atomicAdd(&gcur[i], hist[i]);
    __syncthreads();
    for (int e = e0 + tid; e < e1; e += 256) {
        int d = dst[e];
        int s = src[e];
        int b = d >> 9;
        int r = atomicAdd(&rk[b], 1);
        part[base[b] + r] = ((d & 511) << 17) | s;   // src < 2^17
    }
}

// ---------------- CSR build, pass B: per-bucket LDS sort (prefix fused) ----
__global__ __launch_bounds__(256) void k_build(const int* __restrict__ gcur,
                                               const int* __restrict__ part,
                                               int* __restrict__ csr,
                                               int* __restrict__ off,
                                               float* __restrict__ dinv) {
    __shared__ int cnts[256];
    __shared__ int hist[512];
    __shared__ int loff[512];
    __shared__ int ssum[256];
    __shared__ int csrbuf[CAPB];
    int b = blockIdx.x;
    int tid = threadIdx.x;
    cnts[tid] = (tid < NBUCK) ? gcur[tid] : 0;       // inline bucket prefix
    __syncthreads();
    for (int st = 1; st < 256; st <<= 1) {
        int tmp = (tid >= st) ? cnts[tid - st] : 0;
        __syncthreads();
        cnts[tid] += tmp;
        __syncthreads();
    }
    int obase = (b == 0) ? 0 : cnts[b - 1];
    int cnt = gcur[b];
    int pbase = b * CAPB;
    hist[tid] = 0; hist[tid + 256] = 0;
    __syncthreads();
    for (int i = tid; i < cnt; i += 256)
        atomicAdd(&hist[part[pbase + i] >> 17], 1);
    __syncthreads();
    int a0 = hist[2 * tid], a1 = hist[2 * tid + 1];
    int pairs = a0 + a1;
    ssum[tid] = pairs;
    __syncthreads();
    for (int st = 1; st < 256; st <<= 1) {
        int tmp = (tid >= st) ? ssum[tid - st] : 0;
        __syncthreads();
        ssum[tid] += tmp;
        __syncthreads();
    }
    int pexcl = ssum[tid] - pairs;
    loff[2 * tid] = pexcl;
    loff[2 * tid + 1] = pexcl + a0;
    __syncthreads();
    for (int i = tid; i < 512; i += 256) {
        int d = b * 512 + i;
        if (d < NN) {
            int c = hist[i];
            off[d] = obase + loff[i] + c;            // end of row d
            dinv[d] = rsqrtf((float)(c + 1));        // +1 self-loop
        }
    }
    hist[tid] = 0; hist[tid + 256] = 0;              // reuse as rank counters
    __syncthreads();
    for (int i = tid; i < cnt; i += 256) {
        int rec = part[pbase + i];
        int dl = rec >> 17;
        int r = atomicAdd(&hist[dl], 1);
        csrbuf[loff[dl] + r] = rec & 0x1FFFF;
    }
    __syncthreads();
    for (int i = tid; i < cnt; i += 256)             // coalesced flush
        csr[obase + i] = csrbuf[i];
}

// ---------------- hw1' = dinv * ([x|pos] @ W1)  (80 -> 64), MFMA bf16-split
// bf16 hi/lo split (Ahi*Bhi + Ahi*Blo + Alo*Bhi) -> fp32-class accuracy.
#define HW1_K 104
__global__ __launch_bounds__(256) void k_hw1(const float* __restrict__ x,
                                             const float* __restrict__ pos,
                                             const float* __restrict__ W1,
                                             const float* __restrict__ dinv,
                                             __half* __restrict__ hw1) {
    __shared__ unsigned short ahi[64 * HW1_K];
    __shared__ unsigned short alo[64 * HW1_K];
    __shared__ unsigned short bhi[64 * HW1_K];
    __shared__ unsigned short blo[64 * HW1_K];
    __shared__ float sdin[64];
    int tid = threadIdx.x;
    int nb = blockIdx.x * 64;
    for (int i = tid; i < 64 * 24; i += 256) {
        int r = i / 24, c = i - r * 24;
        ahi[r * HW1_K + 80 + c] = 0; alo[r * HW1_K + 80 + c] = 0;
        bhi[r * HW1_K + 80 + c] = 0; blo[r * HW1_K + 80 + c] = 0;
    }
    for (int i = tid; i < 64 * 64; i += 256) {
        int r = i >> 6, c = i & 63;
        int g = nb + r;
        float v = (g < NN) ? x[g * 64 + c] : 0.0f;
        unsigned short h = bf16hi(v);
        ahi[r * HW1_K + c] = h;
        alo[r * HW1_K + c] = bf16hi(v - bf16tof(h));
    }
    for (int i = tid; i < 64 * 16; i += 256) {
        int r = i >> 4, c = i & 15;
        int g = nb + r;
        float v = (g < NN) ? pos[g * 16 + c] : 0.0f;
        unsigned short h = bf16hi(v);
        ahi[r * HW1_K + 64 + c] = h;
        alo[r * HW1_K + 64 + c] = bf16hi(v - bf16tof(h));
    }
    for (int i = tid; i < 80 * 64; i += 256) {
        int k = i >> 6, c = i & 63;
        float v = W1[i];
        unsigned short h = bf16hi(v);
        bhi[c * HW1_K + k] = h;
        blo[c * HW1_K + k] = bf16hi(v - bf16tof(h));
    }
    for (int i = tid; i < 64; i += 256) {
        int g = nb + i;
        sdin[i] = (g < NN) ? dinv[g] : 0.0f;
    }
    __syncthreads();
    int wave = tid >> 6, lane = tid & 63;
    int frow = lane & 15, fq = lane >> 4;
    int r0 = wave * 16;                        // wave owns 16 rows x 64 cols
    int aoff = (r0 + frow) * HW1_K + fq * 8;
    s16x8 ah0 = *(s16x8*)&ahi[aoff];
    s16x8 ah1 = *(s16x8*)&ahi[aoff + 32];
    s16x8 ah2 = *(s16x8*)&ahi[aoff + 64];
    s16x8 al0 = *(s16x8*)&alo[aoff];
    s16x8 al1 = *(s16x8*)&alo[aoff + 32];
    s16x8 al2 = *(s16x8*)&alo[aoff + 64];
    f32x4 acc[4];
#pragma unroll
    for (int ct = 0; ct < 4; ++ct) {
        acc[ct] = (f32x4)(0.0f);
        int boff = (ct * 16 + frow) * HW1_K + fq * 8;
        s16x8 bh0 = *(s16x8*)&bhi[boff];
        s16x8 bh1 = *(s16x8*)&bhi[boff + 32];
        s16x8 bh2 = *(s16x8*)&bhi[boff + 64];
        s16x8 bl0 = *(s16x8*)&blo[boff];
        s16x8 bl1 = *(s16x8*)&blo[boff + 32];
        s16x8 bl2 = *(s16x8*)&blo[boff + 64];
        acc[ct] = __builtin_amdgcn_mfma_f32_16x16x32_bf16(ah0, bh0, acc[ct], 0, 0, 0);
        acc[ct] = __builtin_amdgcn_mfma_f32_16x16x32_bf16(ah1, bh1, acc[ct], 0, 0, 0);
        acc[ct] = __builtin_amdgcn_mfma_f32_16x16x32_bf16(ah2, bh2, acc[ct], 0, 0, 0);
        acc[ct] = __builtin_amdgcn_mfma_f32_16x16x32_bf16(ah0, bl0, acc[ct], 0, 0, 0);
        acc[ct] = __builtin_amdgcn_mfma_f32_16x16x32_bf16(ah1, bl1, acc[ct], 0, 0, 0);
        acc[ct] = __builtin_amdgcn_mfma_f32_16x16x32_bf16(ah2, bl2, acc[ct], 0, 0, 0);
        acc[ct] = __builtin_amdgcn_mfma_f32_16x16x32_bf16(al0, bh0, acc[ct], 0, 0, 0);
        acc[ct] = __builtin_amdgcn_mfma_f32_16x16x32_bf16(al1, bh1, acc[ct], 0, 0, 0);
        acc[ct] = __builtin_amdgcn_mfma_f32_16x16x32_bf16(al2, bh2, acc[ct], 0, 0, 0);
    }
#pragma unroll
    for (int ct = 0; ct < 4; ++ct) {
        int col = ct * 16 + frow;
#pragma unroll
        for (int i = 0; i < 4; ++i) {
            int r = r0 + fq * 4 + i;           // C/D: col=lane&15, row=(lane>>4)*4+i
            int g = nb + r;
            if (g < NN)
                hw1[g * 64 + col] = __float2half_rn(acc[ct][i] * sdin[r]);
        }
    }
}

// ---------------- layer-1 gather + FUSED hw2 row-GEMM ----------------------
// Gather loop = proven R18 masked 16-deep (at the ~30 req/ns chip random-line
// ceiling; R3: deepening 8->16 gained 5%, FETCH flat — do not restructure).
// Fusion: hw2[d] = dinv[d]*(h2[d] @ W2) is ROW-LOCAL, and after the gather
// each wave holds the full h2 row (lane = channel, unrounded f32). So the
// k_hw2 dispatch, the h2 buffer, and its 25.6 MB write+read round trip are
// all deleted. Epilogue: row -> wave-private LDS, 32 FMA/lane (halves split
// the k-sum), one shfl_xor(32), fp16 store of the 32-col hw2 row.
// Landmines: R15 channel-slice 3.2x; R16 index arrays 5x (spill); R6 mega
// 4.4x; R7 bucket-scatter 4.8x (TLP collapse: gathers need ~100k waves).
__global__ __launch_bounds__(256) void k_gather1(const int* __restrict__ off,
                                                 const int* __restrict__ csr,
                                                 const float* __restrict__ dinv,
                                                 const __half* __restrict__ hw,
                                                 const float* __restrict__ b1,
                                                 const float* __restrict__ W2,
                                                 __half* __restrict__ hw2out) {
    __shared__ float sW2[64 * 32];             // 8 KB
    __shared__ float h2row[4][64];             // 1 KB, wave-private rows
    int tid = threadIdx.x;
    for (int t = tid; t < 64 * 32; t += 256) sW2[t] = W2[t];
    int lane = tid & 63;
    int wave = tid >> 6;
    int d = blockIdx.x * 4 + wave;             // grid = NN/4 exactly
    int start = (d == 0) ? 0 : off[d - 1];
    int end = off[d];
    start = __builtin_amdgcn_readfirstlane(start);   // SGPR bounds ->
    end   = __builtin_amdgcn_readfirstlane(end);     // scalar csr loads
    float dd = dinv[d];
    float hself = __half2float(hw[d * 64 + lane]);   // hoisted
    __syncthreads();                           // sW2 visible to all waves
    float acc0 = 0.0f, acc1 = 0.0f, acc2 = 0.0f, acc3 = 0.0f;
    for (int e = start; e < end; e += 16) {
        int rem = end - e;                     // >= 1 (SGPR)
        int s0 = csr[e];
        int s1  = (rem > 1)  ? csr[e + 1]  : s0;
        int s2  = (rem > 2)  ? csr[e + 2]  : s0;
        int s3  = (rem > 3)  ? csr[e + 3]  : s0;
        int s4  = (rem > 4)  ? csr[e + 4]  : s0;
        int s5  = (rem > 5)  ? csr[e + 5]  : s0;
        int s6  = (rem > 6)  ? csr[e + 6]  : s0;
        int s7  = (rem > 7)  ? csr[e + 7]  : s0;
        int s8  = (rem > 8)  ? csr[e + 8]  : s0;
        int s9  = (rem > 9)  ? csr[e + 9]  : s0;
        int s10 = (rem > 10) ? csr[e + 10] : s0;
        int s11 = (rem > 11) ? csr[e + 11] : s0;
        int s12 = (rem > 12) ? csr[e + 12] : s0;
        int s13 = (rem > 13) ? csr[e + 13] : s0;
        int s14 = (rem > 14) ? csr[e + 14] : s0;
        int s15 = (rem > 15) ? csr[e + 15] : s0;
        float g0  = __half2float(hw[s0  * 64 + lane]);
        float g1  = __half2float(hw[s1  * 64 + lane]);
        float g2  = __half2float(hw[s2  * 64 + lane]);
        float g3  = __half2float(hw[s3  * 64 + lane]);
        float g4  = __half2float(hw[s4  * 64 + lane]);
        float g5  = __half2float(hw[s5  * 64 + lane]);
        float g6  = __half2float(hw[s6  * 64 + lane]);
        float g7  = __half2float(hw[s7  * 64 + lane]);
        float g8  = __half2float(hw[s8  * 64 + lane]);
        float g9  = __half2float(hw[s9  * 64 + lane]);
        float g10 = __half2float(hw[s10 * 64 + lane]);
        float g11 = __half2float(hw[s11 * 64 + lane]);
        float g12 = __half2float(hw[s12 * 64 + lane]);
        float g13 = __half2float(hw[s13 * 64 + lane]);
        float g14 = __half2float(hw[s14 * 64 + lane]);
        float g15 = __half2float(hw[s15 * 64 + lane]);
        int inv = 16 - rem;
        if (inv < 0) inv = 0;                  // # clamped slots (SGPR)
        acc0 += g0;  acc1 += g1;  acc2 += g2;  acc3 += g3;
        acc0 += g4;  acc1 += g5;  acc2 += g6;  acc3 += g7;
        acc0 += g8;  acc1 += g9;  acc2 += g10; acc3 += g11;
        acc0 += g12; acc1 += g13; acc2 += g14; acc3 += g15;
        acc3 = fmaf(-(float)inv, g0, acc3);    // remove clamped duplicates
    }
    // h2 row value for (d, lane), unrounded f32 (closer to ref than fp16)
    float v = fmaxf(b1[lane] + dd * (((acc0 + acc1) + (acc2 + acc3)) + hself), 0.0f);
    h2row[wave][lane] = v;                     // wave-private: no barrier
    // hw2[d][j] = dd * sum_k h2[k]*W2[k][j]; halves split the k-range.
    int j = lane & 31;
    int half = lane >> 5;
    float sum = 0.0f;
#pragma unroll
    for (int k = 0; k < 32; ++k) {
        int kk = half * 32 + k;
        sum += h2row[wave][kk] * sW2[kk * 32 + j];   // bcast + 2-way (free)
    }
    sum += __shfl_xor(sum, 32, 64);            // combine k-halves
    if (half == 0)
        hw2out[d * 32 + j] = __float2half_rn(sum * dd);
}

// ---------------- layer-2 gather (R18 masked 16-deep) + z + linkpred dots --
__global__ __launch_bounds__(256) void k_gather2(const int* __restrict__ off,
                                                 const int* __restrict__ csr,
                                                 const float* __restrict__ dinv,
                                                 const __half* __restrict__ hw,
                                                 const float* __restrict__ b2,
                                                 const float* __restrict__ Wl,
                                                 float* __restrict__ outz,
                                                 float* __restrict__ uu,
                                                 float* __restrict__ vv) {
    int lane = threadIdx.x & 63;
    int half = lane >> 5;
    int j = lane & 31;
    int wave = threadIdx.x >> 6;
    int d = blockIdx.x * 4 + wave;             // grid = NN/4 exactly
    int start = (d == 0) ? 0 : off[d - 1];
    int end = off[d];
    start = __builtin_amdgcn_readfirstlane(start);
    end   = __builtin_amdgcn_readfirstlane(end);
    float dd = dinv[d];
    float hself = __half2float(hw[d * 32 + j]);      // hoisted
    float accA = 0.0f, accB = 0.0f, accC = 0.0f, accD = 0.0f;
    for (int e = start; e < end; e += 16) {
        int rem = end - e;                     // >= 1 (SGPR)
        int s0 = csr[e];                       // clamp target (uniform)
        int i1 = e + half;
        int sA = (half      < rem) ? csr[i1]      : s0;
        int sB = (half + 2  < rem) ? csr[i1 + 2]  : s0;
        int sC = (half + 4  < rem) ? csr[i1 + 4]  : s0;
        int sD = (half + 6  < rem) ? csr[i1 + 6]  : s0;
        int sE = (half + 8  < rem) ? csr[i1 + 8]  : s0;
        int sF = (half + 10 < rem) ? csr[i1 + 10] : s0;
        int sG = (half + 12 < rem) ? csr[i1 + 12] : s0;
        int sH = (half + 14 < rem) ? csr[i1 + 14] : s0;
        float gA = __half2float(hw[sA * 32 + j]);
        float gB = __half2float(hw[sB * 32 + j]);
        float gC = __half2float(hw[sC * 32 + j]);
        float gD = __half2float(hw[sD * 32 + j]);
        float gE = __half2float(hw[sE * 32 + j]);
        float gF = __half2float(hw[sF * 32 + j]);
        float gG = __half2float(hw[sG * 32 + j]);
        float gH = __half2float(hw[sH * 32 + j]);
        int nv = (rem - half + 1) >> 1;        // valid slots this half
        if (nv > 8) nv = 8;
        int inv = 8 - nv;                      // clamped slots this half
        accA += gA; accB += gB; accC += gC; accD += gD;
        accA += gE; accB += gF; accC += gG; accD += gH;
        accD = fmaf(-(float)inv, gH, accD);    // gH == r0 whenever inv > 0
    }
    float acc = (accA + accB) + (accC + accD);
    acc += __shfl(acc, lane ^ 32, 64);         // combine halves (full exec)
    float z = b2[j] + dd * (acc + hself);      // valid on all lanes
    if (half == 0)
        outz[d * 32 + j] = z;
    // per-node link-pred dots (all lanes; halves compute identical values)
    float p0 = z * Wl[j];
    float p1 = z * Wl[32 + j];
    p0 += __shfl_xor(p0, 1, 64);  p1 += __shfl_xor(p1, 1, 64);
    p0 += __shfl_xor(p0, 2, 64);  p1 += __shfl_xor(p1, 2, 64);
    p0 += __shfl_xor(p0, 4, 64);  p1 += __shfl_xor(p1, 4, 64);
    p0 += __shfl_xor(p0, 8, 64);  p1 += __shfl_xor(p1, 8, 64);
    p0 += __shfl_xor(p0, 16, 64); p1 += __shfl_xor(p1, 16, 64);
    if (lane == 0) { uu[d] = p0; vv[d] = p1; }
}

// ---------------- link prediction head: pred = u[s] + v[d] + bl ------------
__global__ __launch_bounds__(256) void k_linkpred(const int* __restrict__ sidx,
                                                  const int* __restrict__ didx,
                                                  const float* __restrict__ uu,
                                                  const float* __restrict__ vv,
                                                  const float* __restrict__ bl,
                                                  float* __restrict__ pred) {
    int e = blockIdx.x * 256 + threadIdx.x;
    if (e < NEL)
        pred[e] = uu[sidx[e]] + vv[didx[e]] + bl[0];
}

extern "C" void kernel_launch(void* const* d_in, const int* in_sizes, int n_in,
                              void* d_out, int out_size, void* d_ws, size_t ws_size,
                              hipStream_t stream) {
    const float* x    = (const float*)d_in[0];
    const float* pos  = (const float*)d_in[1];
    const float* W1   = (const float*)d_in[2];
    const float* b1   = (const float*)d_in[3];
    const float* W2   = (const float*)d_in[4];
    const float* b2   = (const float*)d_in[5];
    const float* Wl   = (const float*)d_in[6];
    const float* bl   = (const float*)d_in[7];
    const int*   ei   = (const int*)d_in[8];   // [2, NE]
    const int*   eli  = (const int*)d_in[9];   // [2, NEL]
    const int* src  = ei;
    const int* dst  = ei + NE;
    const int* lsrc = eli;
    const int* ldst = eli + NEL;

    float* out_z    = (float*)d_out;            // [NN, 32]
    float* out_pred = (float*)d_out + NN * 32;  // [NEL]

    // workspace: dinv[NN]f | off[NN]i | gcur[NBUCK] | csr[NE]i |
    //            hw1'[NN*64]h (aliases part[NBUCK*CAPB]i = 8.0 MB, dead after
    //            k_build; also slack for the <=15-int csr over-reads) |
    //            hw2'[NN*32]h | uu[NN]f | vv[NN]f    ~= 28 MB
    //            (h2 buffer DELETED — hw2 is computed in k_gather1's epilogue)
    float*  dinv  = (float*)d_ws;
    int*    off   = (int*)(dinv + NN);
    int*    gcur  = off + NN;
    int*    csr   = gcur + NBUCK;
    __half* hw1   = (__half*)(csr + NE);
    int*    part  = (int*)hw1;                  // 8.0 MB <= hw1's 12.8 MB
    __half* hw2   = hw1 + NN * 64;
    float*  uu    = (float*)(hw2 + NN * 32);
    float*  vv    = uu + NN;

    // 1) CSR build: partition -> per-bucket LDS sort (prefix fused, +dinv)
    hipMemsetAsync(gcur, 0, NBUCK * sizeof(int), stream);
    k_part<<<(NE + TPE - 1) / TPE, 256, 0, stream>>>(src, dst, gcur, part);
    k_build<<<NBUCK, 256, 0, stream>>>(gcur, part, csr, off, dinv);

    // 2) hw1' = dinv * ([x|pos] @ W1), MFMA bf16-split (part now dead)
    k_hw1<<<(NN + TM - 1) / TM, 256, 0, stream>>>(x, pos, W1, dinv, hw1);

    // 3) layer-1 gather + relu + FUSED hw2 row-GEMM -> hw2 (fp16)
    k_gather1<<<NN / 4, 256, 0, stream>>>(off, csr, dinv, hw1, b1, W2, hw2);

    // 4) layer-2 gather + bias -> z (fp32 out) + per-node linkpred dots u,v
    k_gather2<<<NN / 4, 256, 0, stream>>>(off, csr, dinv, hw2, b2, Wl,
                                          out_z, uu, vv);

    // 5) link prediction: pred = u[s] + v[d] + bl
    k_linkpred<<<(NEL + 255) / 256, 256, 0, stream>>>(lsrc, ldst, uu, vv, bl,
                                                      out_pred);
}